// Round 16
// baseline (128.097 us; speedup 1.0000x reference)
//
#include <hip/hip_runtime.h>
#include <cstdint>
#include <cstddef>

#define E_TOT 2048
#define A_TOT 512
#define FEAT  128
#define N_UP  1024
#define K_RBF 32
#define DIM   256

typedef float vfloat4 __attribute__((ext_vector_type(4)));

// ---------------------------------------------------------------------------
// Main pass, 16KB-single-burst variant. Block owns (EB=16 e x AB=128 a),
// 4 waves, grid 512 (2 blocks/CU, 8 waves/CU). Wave owns 32 consecutive
// atoms; per e it issues ONE 16-load back-to-back nt burst (16KB contiguous)
// into a SINGLE buffer B[16] (~64 VGPR; R9's dual-buffer 16-burst spilled).
// Latency is hidden across waves (2/SIMD alternate process/burst), not by
// intra-wave ping-pong. #pragma unroll 1 on the e-loop prevents the R14
// full-unroll register blowup. Zero barriers in hot loop. elec-partial:
// intra-wave shfl_down(32) + LDS atomicAdd combine. atom-partial: 16 vfloat4
// register accumulators -> ws_atom[A_TOT][GE][FEAT] (finals reads contiguous
// spans per atom).
// ---------------------------------------------------------------------------
template <int EB>
__global__ __launch_bounds__(256) void main_pass(
    const float* __restrict__ h, const float* __restrict__ r_im,
    const float* __restrict__ mu, const float* __restrict__ sigma,
    float* __restrict__ ws_atom,   // [A_TOT][GE][FEAT]
    float* __restrict__ ws_elec) { // [GA][E_TOT][FEAT]
  constexpr int AB = 128;
  constexpr int GA = A_TOT / AB;  // 4
  constexpr int GE = E_TOT / EB;
  const int bid = blockIdx.x;
  const int g_a = bid % GA, g_e = bid / GA;
  const int e0 = g_e * EB, a0 = g_a * AB;
  const int t = threadIdx.x;
  const int wave = t >> 6, lane = t & 63;
  const int f4 = lane & 31, r_lo = lane >> 5;

  __shared__ float s_mu[K_RBF], s_inv[K_RBF];
  __shared__ float rbf_lds[EB * AB];
  __shared__ float esum_lds[EB * FEAT];

  if (t < K_RBF) {
    s_mu[t] = mu[t];
    float s = sigma[t];
    float sp = (s > 20.0f) ? s : log1pf(__expf(s));  // softplus
    s_inv[t] = 1.0f / sp;
  }
  __syncthreads();

  for (int i = t; i < EB * FEAT; i += 256) esum_lds[i] = 0.0f;
  for (int i = t; i < EB * AB; i += 256) {
    int e_l = i / AB, a_l = i % AB;
    float rv = r_im[(size_t)(e0 + e_l) * A_TOT + a0 + a_l];
    float acc = 0.0f;
#pragma unroll
    for (int k = 0; k < K_RBF; ++k) {
      float d = rv - s_mu[k];
      acc += __expf(-d * d * s_inv[k]);
    }
    rbf_lds[i] = acc * (1.0f / K_RBF);
  }
  __syncthreads();  // hot loop below is barrier-free

  vfloat4 acc[16];
#pragma unroll
  for (int i = 0; i < 16; ++i) acc[i] = (vfloat4)(0.f);

  // per-lane base: atom wave*32 + r_lo, feature f4*4
  const float* hbase = h + ((size_t)e0 * A_TOT + a0) * FEAT +
                       (wave * 32 + r_lo) * FEAT + f4 * 4;
  const int arb = wave * 32 + r_lo;

  vfloat4 B[16];
#pragma unroll 1
  for (int e = 0; e < EB; ++e) {
    const float* pe = hbase + (size_t)e * (A_TOT * FEAT);
    // one 16-instruction back-to-back burst: 16KB contiguous per wave
#pragma unroll
    for (int i = 0; i < 16; ++i) {
      B[i] = __builtin_nontemporal_load(
          reinterpret_cast<const vfloat4*>(pe + i * (2 * FEAT)));
    }
    vfloat4 esum = (vfloat4)(0.f);
#pragma unroll
    for (int i = 0; i < 16; ++i) {
      float rb = rbf_lds[e * AB + arb + i * 2];
      vfloat4 v = B[i] * rb;
      acc[i] += v;
      esum += v;
    }
    esum.x += __shfl_down(esum.x, 32, 64);
    esum.y += __shfl_down(esum.y, 32, 64);
    esum.z += __shfl_down(esum.z, 32, 64);
    esum.w += __shfl_down(esum.w, 32, 64);
    if (lane < 32) {
      float* p = &esum_lds[e * FEAT + f4 * 4];
      atomicAdd(p + 0, esum.x);
      atomicAdd(p + 1, esum.y);
      atomicAdd(p + 2, esum.z);
      atomicAdd(p + 3, esum.w);
    }
  }

  // atom partials -> [A_TOT][GE][FEAT] (finals reads contiguous spans)
  vfloat4* ws_a4 = reinterpret_cast<vfloat4*>(ws_atom);
#pragma unroll
  for (int j = 0; j < 16; ++j) {
    const int a_l = wave * 32 + j * 2 + r_lo;
    ws_a4[((size_t)(a0 + a_l) * GE + g_e) * 32 + f4] = acc[j];
  }

  // combined elec slice write
  __syncthreads();
  vfloat4* ws_e4 = reinterpret_cast<vfloat4*>(ws_elec);
  const vfloat4* es4 = reinterpret_cast<const vfloat4*>(esum_lds);
  for (int i = t; i < EB * 32; i += 256) {
    const int e_l = i >> 5, ff = i & 31;
    ws_e4[((size_t)g_a * E_TOT + e0 + e_l) * 32 + ff] = es4[e_l * 32 + ff];
  }
}

// ---------------------------------------------------------------------------
// R13-exact fallback main pass (nt, 8KB bursts, ping-pong), EB=32/AB=64.
// ---------------------------------------------------------------------------
template <int EB, int AB>
__global__ __launch_bounds__(256) void main_pass_fb(
    const float* __restrict__ h, const float* __restrict__ r_im,
    const float* __restrict__ mu, const float* __restrict__ sigma,
    float* __restrict__ ws_atom,   // [A_TOT][GE][FEAT]
    float* __restrict__ ws_elec) { // [GA][E_TOT][FEAT]
  constexpr int GA = A_TOT / AB;
  constexpr int GE = E_TOT / EB;
  constexpr int NW = AB / 8;
  const int bid = blockIdx.x;
  const int g_a = bid % GA, g_e = bid / GA;
  const int e0 = g_e * EB, a0 = g_a * AB;
  const int t = threadIdx.x;
  const int wave = t >> 6, lane = t & 63;
  const int f4 = lane & 31, r_lo = lane >> 5;

  __shared__ float s_mu[K_RBF], s_inv[K_RBF];
  __shared__ float rbf_lds[EB * AB];
  __shared__ float esum_lds[EB * FEAT];

  if (t < K_RBF) {
    s_mu[t] = mu[t];
    float s = sigma[t];
    float sp = (s > 20.0f) ? s : log1pf(__expf(s));
    s_inv[t] = 1.0f / sp;
  }
  __syncthreads();

  for (int i = t; i < EB * FEAT; i += 256) esum_lds[i] = 0.0f;
  for (int i = t; i < EB * AB; i += 256) {
    int e_l = i / AB, a_l = i % AB;
    float rv = r_im[(size_t)(e0 + e_l) * A_TOT + a0 + a_l];
    float acc = 0.0f;
#pragma unroll
    for (int k = 0; k < K_RBF; ++k) {
      float d = rv - s_mu[k];
      acc += __expf(-d * d * s_inv[k]);
    }
    rbf_lds[i] = acc * (1.0f / K_RBF);
  }
  __syncthreads();

  vfloat4 acc[NW];
#pragma unroll
  for (int i = 0; i < NW; ++i) acc[i] = (vfloat4)(0.f);

  const int aw = wave * (AB / 4);
  const float* hbase = h + ((size_t)e0 * A_TOT + a0 + aw + r_lo) * FEAT + f4 * 4;
  const int arb = aw + r_lo;

  auto ldall = [&](vfloat4* buf, int e) {
#pragma unroll
    for (int i = 0; i < NW; ++i) {
      const float* p = hbase + (size_t)e * (A_TOT * FEAT) + i * (2 * FEAT);
      buf[i] = __builtin_nontemporal_load(reinterpret_cast<const vfloat4*>(p));
    }
  };
  auto prall = [&](const vfloat4* buf, int e) {
    vfloat4 esum = (vfloat4)(0.f);
#pragma unroll
    for (int i = 0; i < NW; ++i) {
      float rb = rbf_lds[e * AB + arb + i * 2];
      vfloat4 v = buf[i] * rb;
      acc[i] += v;
      esum += v;
    }
    esum.x += __shfl_down(esum.x, 32, 64);
    esum.y += __shfl_down(esum.y, 32, 64);
    esum.z += __shfl_down(esum.z, 32, 64);
    esum.w += __shfl_down(esum.w, 32, 64);
    if (lane < 32) {
      float* p = &esum_lds[e * FEAT + f4 * 4];
      atomicAdd(p + 0, esum.x);
      atomicAdd(p + 1, esum.y);
      atomicAdd(p + 2, esum.z);
      atomicAdd(p + 3, esum.w);
    }
  };

  vfloat4 B0[NW], B1[NW];
  ldall(B0, 0);
  for (int e = 0; e < EB; e += 2) {
    if (e + 1 < EB) ldall(B1, e + 1);
    prall(B0, e);
    if (e + 2 < EB) ldall(B0, e + 2);
    prall(B1, e + 1);
  }

  vfloat4* ws_a4 = reinterpret_cast<vfloat4*>(ws_atom);
#pragma unroll
  for (int j = 0; j < NW; ++j) {
    const int a_l = aw + j * 2 + r_lo;
    ws_a4[((size_t)(a0 + a_l) * GE + g_e) * 32 + f4] = acc[j];
  }

  __syncthreads();
  vfloat4* ws_e4 = reinterpret_cast<vfloat4*>(ws_elec);
  const vfloat4* es4 = reinterpret_cast<const vfloat4*>(esum_lds);
  for (int i = t; i < EB * 32; i += 256) {
    const int e_l = i >> 5, ff = i & 31;
    ws_e4[((size_t)g_a * E_TOT + e0 + e_l) * 32 + ff] = es4[e_l * 32 + ff];
  }
}

// ---------------------------------------------------------------------------
// Merged epilogue. Blocks [0, A_TOT): block a reads its contiguous
// ws_atom[a][*][*] -> spin means, 256-dot, tanh*gain.
// Blocks [A_TOT, A_TOT+256): elec slice reduce.
// ---------------------------------------------------------------------------
__global__ __launch_bounds__(256) void finals(
    const float* __restrict__ ws_atom, const float* __restrict__ ws_elec,
    const float* __restrict__ W, const float* __restrict__ bias,
    float* __restrict__ out, int ge_total, int slices) {
  const int t = threadIdx.x;
  if (blockIdx.x < A_TOT) {
    const int a = blockIdx.x;
    __shared__ float s_in[2 * FEAT];
    const int spin = t >> 7;
    const int f = t & 127;
    const int gh = ge_total >> 1;
    const int g0 = spin * gh;
    const float* base = ws_atom + ((size_t)a * ge_total + g0) * FEAT + f;
    float acc = 0.0f;
#pragma unroll 4
    for (int g = 0; g < gh; ++g) {
      acc += base[(size_t)g * FEAT];
    }
    s_in[t] = acc * (1.0f / (float)N_UP);
    __syncthreads();
    float o = bias[t];
#pragma unroll 4
    for (int k = 0; k < 2 * FEAT; ++k) {
      o += s_in[k] * W[(size_t)k * DIM + t];
    }
    out[(size_t)a * DIM + t] = tanhf(o) * (5.0f / 3.0f);
  } else {
    const int idx = (int)(blockIdx.x - A_TOT) * 256 + t;  // vfloat4 index
    const int n4 = E_TOT * FEAT / 4;
    const vfloat4* in4 = reinterpret_cast<const vfloat4*>(ws_elec);
    vfloat4 s = (vfloat4)(0.f);
    for (int g = 0; g < slices; ++g) {
      s += in4[(size_t)g * n4 + idx];
    }
    s *= (1.0f / (float)A_TOT);
    reinterpret_cast<vfloat4*>(out + (size_t)A_TOT * DIM)[idx] = s;
  }
}

// ---------------------------------------------------------------------------
extern "C" void kernel_launch(void* const* d_in, const int* in_sizes, int n_in,
                              void* d_out, int out_size, void* d_ws, size_t ws_size,
                              hipStream_t stream) {
  const float* h     = (const float*)d_in[0];  // (2048,512,128)
  const float* r_im  = (const float*)d_in[1];  // (2048,512)
  const float* mu    = (const float*)d_in[2];  // (32,)
  const float* sigma = (const float*)d_in[3];  // (32,)
  const float* W     = (const float*)d_in[4];  // (256,256)
  const float* b     = (const float*)d_in[5];  // (256,)
  float* out = (float*)d_out;

  float* ws_atom = (float*)d_ws;
  const int finals_grid = A_TOT + (E_TOT * FEAT / 4) / 256;  // 512 + 256

  // preferred: EB=16, AB=128 -> GE=128, GA=4, grid 512, ws = 33.5+4 = 37.7 MB
  const size_t need16 = ((size_t)A_TOT * (E_TOT / 16) * FEAT +
                         (size_t)4 * E_TOT * FEAT) * 4;
  if (ws_size >= need16) {
    constexpr int GE = E_TOT / 16, GA = 4;  // 128, 4
    float* ws_elec = ws_atom + (size_t)A_TOT * GE * FEAT;
    main_pass<16><<<GE * GA, 256, 0, stream>>>(h, r_im, mu, sigma, ws_atom, ws_elec);
    finals<<<finals_grid, 256, 0, stream>>>(ws_atom, ws_elec, W, b, out, GE, GA);
  } else {
    // fallback: R13 exact — EB=32, AB=64, grid 512, ws 25.2 MB
    constexpr int GE = E_TOT / 32, GA = A_TOT / 64;  // 64, 8
    float* ws_elec = ws_atom + (size_t)A_TOT * GE * FEAT;
    main_pass_fb<32, 64><<<GE * GA, 256, 0, stream>>>(h, r_im, mu, sigma,
                                                      ws_atom, ws_elec);
    finals<<<finals_grid, 256, 0, stream>>>(ws_atom, ws_elec, W, b, out, GE, GA);
  }
}

// Round 17
// 116.035 us; speedup vs baseline: 1.1040x; 1.1040x over previous
//
#include <hip/hip_runtime.h>
#include <cstdint>
#include <cstddef>

#define E_TOT 2048
#define A_TOT 512
#define FEAT  128
#define N_UP  1024
#define K_RBF 32
#define DIM   256

typedef float vfloat4 __attribute__((ext_vector_type(4)));

// ---------------------------------------------------------------------------
// Main pass, 8-wave variant (best known: R15, 116.1 us). Per-wave structure:
// EB=32, 16 atoms/wave, 8KB contiguous nt-load bursts, ping-pong double
// buffer, barrier-free hot loop. 512-thread blocks: AB=128, 8 waves,
// grid 256 = 1 block/CU, 8 waves/CU. elec-partial: intra-wave shfl_down(32)
// + LDS atomicAdd combine across 8 waves. atom-partial: 8 vfloat4 register
// accumulators -> ws_atom[A_TOT][GE][FEAT].
// ---------------------------------------------------------------------------
template <int EB, int AB, int THREADS>
__global__ __launch_bounds__(THREADS) void main_pass(
    const float* __restrict__ h, const float* __restrict__ r_im,
    const float* __restrict__ mu, const float* __restrict__ sigma,
    float* __restrict__ ws_atom,   // [A_TOT][GE][FEAT]
    float* __restrict__ ws_elec) { // [GA][E_TOT][FEAT]
  constexpr int GA = A_TOT / AB;
  constexpr int GE = E_TOT / EB;
  constexpr int WA = 16;           // atoms per wave
  constexpr int NW = WA / 2;       // vfloat4 loads per wave per e
  static_assert(AB / WA == THREADS / 64, "waves cover AB");
  static_assert(EB % 2 == 0, "EB even");
  const int bid = blockIdx.x;
  const int g_a = bid % GA, g_e = bid / GA;
  const int e0 = g_e * EB, a0 = g_a * AB;
  const int t = threadIdx.x;
  const int wave = t >> 6, lane = t & 63;
  const int f4 = lane & 31, r_lo = lane >> 5;

  __shared__ float s_mu[K_RBF], s_inv[K_RBF];
  __shared__ float rbf_lds[EB * AB];
  __shared__ float esum_lds[EB * FEAT];

  if (t < K_RBF) {
    s_mu[t] = mu[t];
    float s = sigma[t];
    float sp = (s > 20.0f) ? s : log1pf(__expf(s));  // softplus
    s_inv[t] = 1.0f / sp;
  }
  __syncthreads();

  for (int i = t; i < EB * FEAT; i += THREADS) esum_lds[i] = 0.0f;
  for (int i = t; i < EB * AB; i += THREADS) {
    int e_l = i / AB, a_l = i % AB;
    float rv = r_im[(size_t)(e0 + e_l) * A_TOT + a0 + a_l];
    float acc = 0.0f;
#pragma unroll
    for (int k = 0; k < K_RBF; ++k) {
      float d = rv - s_mu[k];
      acc += __expf(-d * d * s_inv[k]);
    }
    rbf_lds[i] = acc * (1.0f / K_RBF);
  }
  __syncthreads();  // hot loop below is barrier-free

  vfloat4 acc[NW];
#pragma unroll
  for (int i = 0; i < NW; ++i) acc[i] = (vfloat4)(0.f);

  // per-lane base: atom wave*WA + r_lo, feature f4*4
  const int aw = wave * WA;
  const float* hbase = h + ((size_t)e0 * A_TOT + a0 + aw + r_lo) * FEAT + f4 * 4;
  const int arb = aw + r_lo;

  auto ldall = [&](vfloat4* buf, int e) {
#pragma unroll
    for (int i = 0; i < NW; ++i) {
      const float* p = hbase + (size_t)e * (A_TOT * FEAT) + i * (2 * FEAT);
      buf[i] = __builtin_nontemporal_load(reinterpret_cast<const vfloat4*>(p));
    }
  };
  auto prall = [&](const vfloat4* buf, int e) {
    vfloat4 esum = (vfloat4)(0.f);
#pragma unroll
    for (int i = 0; i < NW; ++i) {
      float rb = rbf_lds[e * AB + arb + i * 2];
      vfloat4 v = buf[i] * rb;
      acc[i] += v;
      esum += v;
    }
    esum.x += __shfl_down(esum.x, 32, 64);
    esum.y += __shfl_down(esum.y, 32, 64);
    esum.z += __shfl_down(esum.z, 32, 64);
    esum.w += __shfl_down(esum.w, 32, 64);
    if (lane < 32) {
      float* p = &esum_lds[e * FEAT + f4 * 4];
      atomicAdd(p + 0, esum.x);
      atomicAdd(p + 1, esum.y);
      atomicAdd(p + 2, esum.z);
      atomicAdd(p + 3, esum.w);
    }
  };

  vfloat4 B0[NW], B1[NW];
  ldall(B0, 0);
  for (int e = 0; e < EB; e += 2) {
    if (e + 1 < EB) ldall(B1, e + 1);
    prall(B0, e);
    if (e + 2 < EB) ldall(B0, e + 2);
    prall(B1, e + 1);
  }

  // atom partials -> [A_TOT][GE][FEAT]
  vfloat4* ws_a4 = reinterpret_cast<vfloat4*>(ws_atom);
#pragma unroll
  for (int j = 0; j < NW; ++j) {
    const int a_l = aw + j * 2 + r_lo;
    ws_a4[((size_t)(a0 + a_l) * GE + g_e) * 32 + f4] = acc[j];
  }

  // combined elec slice write
  __syncthreads();
  vfloat4* ws_e4 = reinterpret_cast<vfloat4*>(ws_elec);
  const vfloat4* es4 = reinterpret_cast<const vfloat4*>(esum_lds);
  for (int i = t; i < EB * 32; i += THREADS) {
    const int e_l = i >> 5, ff = i & 31;
    ws_e4[((size_t)g_a * E_TOT + e0 + e_l) * 32 + ff] = es4[e_l * 32 + ff];
  }
}

// ---------------------------------------------------------------------------
// Merged epilogue. Blocks [0, A_TOT): block a reads its contiguous
// ws_atom[a][*][*] -> spin means, 256-dot, tanh*gain.
// Blocks [A_TOT, A_TOT+256): elec slice reduce.
// ---------------------------------------------------------------------------
__global__ __launch_bounds__(256) void finals(
    const float* __restrict__ ws_atom, const float* __restrict__ ws_elec,
    const float* __restrict__ W, const float* __restrict__ bias,
    float* __restrict__ out, int ge_total, int slices) {
  const int t = threadIdx.x;
  if (blockIdx.x < A_TOT) {
    const int a = blockIdx.x;
    __shared__ float s_in[2 * FEAT];
    const int spin = t >> 7;
    const int f = t & 127;
    const int gh = ge_total >> 1;
    const int g0 = spin * gh;
    const float* base = ws_atom + ((size_t)a * ge_total + g0) * FEAT + f;
    float acc = 0.0f;
#pragma unroll 4
    for (int g = 0; g < gh; ++g) {
      acc += base[(size_t)g * FEAT];
    }
    s_in[t] = acc * (1.0f / (float)N_UP);
    __syncthreads();
    float o = bias[t];
#pragma unroll 4
    for (int k = 0; k < 2 * FEAT; ++k) {
      o += s_in[k] * W[(size_t)k * DIM + t];
    }
    out[(size_t)a * DIM + t] = tanhf(o) * (5.0f / 3.0f);
  } else {
    const int idx = (int)(blockIdx.x - A_TOT) * 256 + t;  // vfloat4 index
    const int n4 = E_TOT * FEAT / 4;
    const vfloat4* in4 = reinterpret_cast<const vfloat4*>(ws_elec);
    vfloat4 s = (vfloat4)(0.f);
    for (int g = 0; g < slices; ++g) {
      s += in4[(size_t)g * n4 + idx];
    }
    s *= (1.0f / (float)A_TOT);
    reinterpret_cast<vfloat4*>(out + (size_t)A_TOT * DIM)[idx] = s;
  }
}

// ---------------------------------------------------------------------------
extern "C" void kernel_launch(void* const* d_in, const int* in_sizes, int n_in,
                              void* d_out, int out_size, void* d_ws, size_t ws_size,
                              hipStream_t stream) {
  const float* h     = (const float*)d_in[0];  // (2048,512,128)
  const float* r_im  = (const float*)d_in[1];  // (2048,512)
  const float* mu    = (const float*)d_in[2];  // (32,)
  const float* sigma = (const float*)d_in[3];  // (32,)
  const float* W     = (const float*)d_in[4];  // (256,256)
  const float* b     = (const float*)d_in[5];  // (256,)
  float* out = (float*)d_out;

  float* ws_atom = (float*)d_ws;
  const int finals_grid = A_TOT + (E_TOT * FEAT / 4) / 256;  // 512 + 256

  // preferred: EB=32, AB=128, 512 threads -> GE=64, GA=4, grid 256
  // (1 block/CU, 8 waves/CU), ws = 16.8 + 4.2 = 21 MB
  const size_t needA = ((size_t)A_TOT * (E_TOT / 32) * FEAT +
                        (size_t)(A_TOT / 128) * E_TOT * FEAT) * 4;
  if (ws_size >= needA) {
    constexpr int GE = E_TOT / 32, GA = A_TOT / 128;  // 64, 4
    float* ws_elec = ws_atom + (size_t)A_TOT * GE * FEAT;
    main_pass<32, 128, 512><<<GE * GA, 512, 0, stream>>>(h, r_im, mu, sigma,
                                                         ws_atom, ws_elec);
    finals<<<finals_grid, 256, 0, stream>>>(ws_atom, ws_elec, W, b, out, GE, GA);
  } else {
    // fallback: R13 exact — EB=32, AB=64, 256 threads, grid 512
    constexpr int GE = E_TOT / 32, GA = A_TOT / 64;  // 64, 8
    float* ws_elec = ws_atom + (size_t)A_TOT * GE * FEAT;
    main_pass<32, 64, 256><<<GE * GA, 256, 0, stream>>>(h, r_im, mu, sigma,
                                                        ws_atom, ws_elec);
    finals<<<finals_grid, 256, 0, stream>>>(ws_atom, ws_elec, W, b, out, GE, GA);
  }
}